// Round 2
// baseline (217607.788 us; speedup 1.0000x reference)
//
#include <hip/hip_runtime.h>
#include <math.h>

#define N_IMG 1024
#define C_IN 512
#define C_MID 1024
#define HW 7
#define SP 49
#define NCOLS (N_IMG*SP)      /* 50176 */
#define K1 (C_IN*9)           /* 4608 */
#define K2 (C_MID*9 + C_IN)   /* 9728: conv2 + fused 1x1 shortcut */
#define BM 128
#define BN 128
#define BK 16

// ---------------------------------------------------------------------------
// Conv as implicit GEMM: C[oc, col] = sum_k A[oc,k] * im2col[k, col]
// MODE 0: A = w1 (K=4608), B from X, out = h = relu(conv1)
// MODE 1: A = [w2 | wd] (K=9728), B from [im2col(h) | X], out = embedded
// Grid (392, 8), 256 threads, 128x128 tile, 8x8 micro-tile (two 4-wide chunks
// at +0/+64 to keep LDS aliasing <= 2-way, which is free on gfx950).
// Register prefetch of tile t+1 + double-buffered LDS, ONE barrier per tile.
// ---------------------------------------------------------------------------
template<int MODE>
__global__ __launch_bounds__(256, 3)
void conv_gemm(const float* __restrict__ X, const float* __restrict__ Hin,
               const float* __restrict__ W, const float* __restrict__ WD,
               float* __restrict__ out)
{
    constexpr int K = MODE ? K2 : K1;
    constexpr int NT = K / BK;
    __shared__ float As[2][BK][BM+4];
    __shared__ float Bs[2][BK][BN+4];

    const int tid = threadIdx.x;
    const int bn = blockIdx.x, bm = blockIdx.y;
    const int tx = tid & 15, ty = tid >> 4;

    // A staging: thread -> (row arow, 8 consecutive k at acol)
    const int arow = tid >> 1;
    const int acol = (tid & 1) * 8;
    const int grow = bm*BM + arow;

    // B staging: thread -> k-row rk, cols bc + 16*jj (lane-coalesced)
    const int rk = tid >> 4;
    const int bc = tid & 15;

    int nb8[8], iy8[8], ix8[8];
    #pragma unroll
    for (int jj = 0; jj < 8; jj++) {
        int col = bn*BN + bc + 16*jj;
        int n = col / SP;
        int p = col - n*SP;
        int y = p / HW;
        nb8[jj] = n; iy8[jj] = y; ix8[jj] = p - y*HW;
    }

    float4 va0, va1;
    float pb[8];

    auto loadA = [&](int t) {
        int kk = t*BK + acol;
        const float* src;
        if (MODE == 0) {
            src = W + (size_t)grow*K1 + kk;
        } else {
            src = (kk < C_MID*9) ? (W + (size_t)grow*(C_MID*9) + kk)
                                 : (WD + (size_t)grow*C_IN + (kk - C_MID*9));
        }
        va0 = *(const float4*)(src);
        va1 = *(const float4*)(src + 4);
    };
    auto loadB = [&](int t) {
        int k = t*BK + rk;
        if (MODE == 0 || k < C_MID*9) {
            int c = k / 9;
            int r = k - c*9;
            int ky = r/3 - 1;
            int kx = (r - (r/3)*3) - 1;
            const float* SRC = (MODE == 0) ? X : Hin;
            const int CS = (MODE == 0) ? C_IN : C_MID;
            #pragma unroll
            for (int jj = 0; jj < 8; jj++) {
                int iy = iy8[jj] + ky, ix = ix8[jj] + kx;
                float v = 0.f;
                if ((unsigned)iy < HW && (unsigned)ix < HW)
                    v = SRC[((size_t)(nb8[jj]*CS + c)*HW + iy)*HW + ix];
                pb[jj] = v;
            }
        } else {
            int c = k - C_MID*9;
            #pragma unroll
            for (int jj = 0; jj < 8; jj++)
                pb[jj] = X[((size_t)(nb8[jj]*C_IN + c)*HW + iy8[jj])*HW + ix8[jj]];
        }
    };
    auto storeA = [&](int buf) {
        As[buf][acol+0][arow] = va0.x; As[buf][acol+1][arow] = va0.y;
        As[buf][acol+2][arow] = va0.z; As[buf][acol+3][arow] = va0.w;
        As[buf][acol+4][arow] = va1.x; As[buf][acol+5][arow] = va1.y;
        As[buf][acol+6][arow] = va1.z; As[buf][acol+7][arow] = va1.w;
    };
    auto storeB = [&](int buf) {
        #pragma unroll
        for (int jj = 0; jj < 8; jj++) Bs[buf][rk][bc + 16*jj] = pb[jj];
    };

    float acc[8][8];
    #pragma unroll
    for (int i = 0; i < 8; i++)
        #pragma unroll
        for (int j = 0; j < 8; j++) acc[i][j] = 0.f;

    loadA(0); loadB(0);
    storeA(0); storeB(0);
    __syncthreads();

    for (int t = 0; t < NT; t++) {
        int cur = t & 1;
        if (t + 1 < NT) { loadA(t+1); loadB(t+1); }
        #pragma unroll
        for (int kk = 0; kk < BK; kk++) {
            float a[8], b[8];
            *(float4*)&a[0] = *(const float4*)&As[cur][kk][ty*4];
            *(float4*)&a[4] = *(const float4*)&As[cur][kk][64 + ty*4];
            *(float4*)&b[0] = *(const float4*)&Bs[cur][kk][tx*4];
            *(float4*)&b[4] = *(const float4*)&Bs[cur][kk][64 + tx*4];
            #pragma unroll
            for (int i = 0; i < 8; i++)
                #pragma unroll
                for (int j = 0; j < 8; j++)
                    acc[i][j] = fmaf(a[i], b[j], acc[i][j]);
        }
        if (t + 1 < NT) { storeA(cur^1); storeB(cur^1); }
        __syncthreads();
    }

    // ---- epilogue: relu + store NCHW ----
    #pragma unroll
    for (int j = 0; j < 8; j++) {
        int col = bn*BN + ((j < 4) ? tx*4 + j : 64 + tx*4 + (j-4));
        int n = col / SP;
        int p = col - n*SP;
        #pragma unroll
        for (int i = 0; i < 8; i++) {
            int m = bm*BM + ((i < 4) ? ty*4 + i : 64 + ty*4 + (i-4));
            out[((size_t)n*C_MID + m)*SP + p] = fmaxf(acc[i][j], 0.f);
        }
    }
}

// ---------------------------------------------------------------------------
__global__ __launch_bounds__(256)
void pool_kernel(const float* __restrict__ emb, float* __restrict__ flat)
{
    int n = blockIdx.x;
    for (int c = threadIdx.x; c < C_MID; c += 256) {
        const float* p = emb + ((size_t)n*C_MID + c)*SP;
        float s = 0.f;
        #pragma unroll
        for (int i = 0; i < SP; i++) s += p[i];
        flat[n*C_MID + c] = s / 49.0f;
    }
}

// ---------------------------------------------------------------------------
// Per-image heads: 45 dot products (9 cls + 36 reg), softmax, box decode+clip.
// ---------------------------------------------------------------------------
__global__ __launch_bounds__(64)
void head_kernel(const float* __restrict__ flat,
                 const float* __restrict__ cls_w, const float* __restrict__ cls_b,
                 const float* __restrict__ reg_w, const float* __restrict__ reg_b,
                 const float* __restrict__ props,
                 float* __restrict__ cls_out, float* __restrict__ reg_out,
                 float* __restrict__ pbox, float* __restrict__ pscore)
{
    int n = blockIdx.x;
    __shared__ float f[C_MID];
    __shared__ float logits[9];
    __shared__ float regs[36];
    for (int c = threadIdx.x; c < C_MID; c += 64) f[c] = flat[n*C_MID + c];
    __syncthreads();
    int o = threadIdx.x;
    if (o < 45) {
        const float* w = (o < 9) ? (cls_w + o*C_MID) : (reg_w + (o-9)*C_MID);
        float a = (o < 9) ? cls_b[o] : reg_b[o-9];
        for (int c = 0; c < C_MID; c++) a = fmaf(f[c], w[c], a);
        if (o < 9) { cls_out[n*9 + o] = a; logits[o] = a; }
        else       { reg_out[n*36 + (o-9)] = a; regs[o-9] = a; }
    }
    __syncthreads();
    if (o < 9) {
        float m = logits[0];
        for (int i = 1; i < 9; i++) m = fmaxf(m, logits[i]);
        float se = 0.f;
        for (int i = 0; i < 9; i++) se += expf(logits[i] - m);
        pscore[n*9 + o] = expf(logits[o] - m) / se;
        {
            #pragma clang fp contract(off)
            float x1 = props[n*4+0], y1 = props[n*4+1];
            float x2 = props[n*4+2], y2 = props[n*4+3];
            float pw = x2 - x1, ph = y2 - y1;
            float pcx = x1 + 0.5f*pw, pcy = y1 + 0.5f*ph;
            float dx = regs[o*4+0] / 10.0f;
            float dy = regs[o*4+1] / 10.0f;
            float dw = fminf(regs[o*4+2] / 5.0f, 4.135166556742356f);
            float dh = fminf(regs[o*4+3] / 5.0f, 4.135166556742356f);
            float ncx = dx*pw + pcx, ncy = dy*ph + pcy;
            float nw = expf(dw)*pw,  nh = expf(dh)*ph;
            float bx1 = ncx - 0.5f*nw, by1 = ncy - 0.5f*nh;
            float bx2 = ncx + 0.5f*nw, by2 = ncy + 0.5f*nh;
            bx1 = fminf(fmaxf(bx1, 0.f), 640.f);
            by1 = fminf(fmaxf(by1, 0.f), 384.f);
            bx2 = fminf(fmaxf(bx2, 0.f), 640.f);
            by2 = fminf(fmaxf(by2, 0.f), 384.f);
            float* dst = pbox + (n*9 + o)*4;
            dst[0] = bx1; dst[1] = by1; dst[2] = bx2; dst[3] = by2;
        }
    }
}

// ---------------------------------------------------------------------------
// Per-image (2 blocks): candidate mask -> bitonic sort of 4096 (score desc,
// idx asc, matching lax.top_k ties) -> top-512 -> IoU bitmask (class-offset
// boxes, exact reference formula) -> serial greedy NMS -> first 100 kept.
// ---------------------------------------------------------------------------
__global__ __launch_bounds__(1024)
void nms_kernel(const float* __restrict__ pbox, const float* __restrict__ pscore,
                float* __restrict__ dbox, float* __restrict__ dsc,
                float* __restrict__ dlab, float* __restrict__ dval)
{
    #pragma clang fp contract(off)
    const int b = blockIdx.x;
    const int tid = threadIdx.x;
    __shared__ unsigned long long mbuf[4096];   // 32 KB: sort arrays, then masks
    __shared__ float s512[512];
    __shared__ int   id512[512];
    __shared__ float obx[512][4];
    __shared__ unsigned long long keepw[8];
    float* sc = (float*)mbuf;
    int*   si = (int*)(sc + 4096);
    const float NEG_INF = -__builtin_inff();

    for (int i = tid; i < 4096; i += 1024) {
        int p = i >> 3;
        int c = (i & 7) + 1;
        int n = b*512 + p;
        float s = pscore[n*9 + c];
        const float* bb = pbox + (n*9 + c)*4;
        float w = bb[2] - bb[0], h = bb[3] - bb[1];
        bool valid = (s > 0.05f) && (w >= 0.01f) && (h >= 0.01f);
        sc[i] = valid ? s : NEG_INF;
        si[i] = i;
    }
    __syncthreads();
    for (int k = 2; k <= 4096; k <<= 1) {
        for (int j = k >> 1; j > 0; j >>= 1) {
            for (int i = tid; i < 4096; i += 1024) {
                int ixj = i ^ j;
                if (ixj > i) {
                    float s1 = sc[i], s2 = sc[ixj];
                    int i1 = si[i], i2 = si[ixj];
                    bool before12 = (s1 > s2) || ((s1 == s2) && (i1 < i2));
                    bool up = ((i & k) == 0);
                    if (up ? !before12 : before12) {
                        sc[i] = s2; sc[ixj] = s1;
                        si[i] = i2; si[ixj] = i1;
                    }
                }
            }
            __syncthreads();
        }
    }
    if (tid < 512) {
        float s = sc[tid];
        int id = si[tid];
        s512[tid] = s;
        id512[tid] = id;
        int c = (id & 7) + 1;
        int n = b*512 + (id >> 3);
        float off = (float)c * 641.0f;   // (max(H,W)+1) * label
        const float* bb = pbox + (n*9 + c)*4;
        obx[tid][0] = bb[0] + off;
        obx[tid][1] = bb[1] + off;
        obx[tid][2] = bb[2] + off;
        obx[tid][3] = bb[3] + off;
    }
    __syncthreads();
    unsigned long long* mask = mbuf;   // [512][8]
    for (int idx = tid; idx < 4096; idx += 1024) {
        int i = idx >> 3, w = idx & 7;
        float ax1 = obx[i][0], ay1 = obx[i][1], ax2 = obx[i][2], ay2 = obx[i][3];
        float aarea = (ax2 - ax1) * (ay2 - ay1);
        unsigned long long m = 0;
        int j0 = w << 6;
        for (int jj = 0; jj < 64; jj++) {
            int j = j0 + jj;
            if (j > i) {
                float bx1 = obx[j][0], by1 = obx[j][1];
                float bx2 = obx[j][2], by2 = obx[j][3];
                float barea = (bx2 - bx1) * (by2 - by1);
                float lx = fmaxf(ax1, bx1), ly = fmaxf(ay1, by1);
                float rx = fminf(ax2, bx2), ry = fminf(ay2, by2);
                float iw = fmaxf(rx - lx, 0.f), ih = fmaxf(ry - ly, 0.f);
                float inter = iw * ih;
                float iou = inter / fmaxf(aarea + barea - inter, 1e-8f);
                if (iou > 0.5f) m |= (1ull << jj);
            }
        }
        mask[(i << 3) + w] = m;
    }
    if (tid < 8) {
        unsigned long long kw = 0;
        for (int jj = 0; jj < 64; jj++)
            if (s512[(tid << 6) + jj] != NEG_INF) kw |= (1ull << jj);
        keepw[tid] = kw;
    }
    __syncthreads();
    if (tid == 0) {
        for (int i = 0; i < 512; i++) {
            if ((keepw[i >> 6] >> (i & 63)) & 1ull) {
                const unsigned long long* mi = mask + (i << 3);
                #pragma unroll
                for (int w = 0; w < 8; w++) keepw[w] &= ~mi[w];
            }
        }
        int cnt = 0;
        for (int i = 0; i < 512 && cnt < 100; i++) {
            if ((keepw[i >> 6] >> (i & 63)) & 1ull) {
                int id = id512[i];
                int c = (id & 7) + 1;
                int n = b*512 + (id >> 3);
                const float* bb = pbox + (n*9 + c)*4;
                float* db = dbox + (b*100 + cnt)*4;
                db[0] = bb[0]; db[1] = bb[1]; db[2] = bb[2]; db[3] = bb[3];
                dsc[b*100 + cnt] = s512[i];
                dlab[b*100 + cnt] = (float)c;
                dval[b*100 + cnt] = 1.0f;
                cnt++;
            }
        }
        for (; cnt < 100; cnt++) {
            float* db = dbox + (b*100 + cnt)*4;
            db[0] = 0.f; db[1] = 0.f; db[2] = 0.f; db[3] = 0.f;
            dsc[b*100 + cnt] = 0.f;
            dlab[b*100 + cnt] = 0.f;
            dval[b*100 + cnt] = 0.f;
        }
    }
}

// ---------------------------------------------------------------------------
extern "C" void kernel_launch(void* const* d_in, const int* in_sizes, int n_in,
                              void* d_out, int out_size, void* d_ws, size_t ws_size,
                              hipStream_t stream)
{
    const float* X      = (const float*)d_in[0];
    const float* props  = (const float*)d_in[1];
    const float* w1     = (const float*)d_in[2];
    const float* w2     = (const float*)d_in[3];
    const float* wd     = (const float*)d_in[4];
    const float* cls_w  = (const float*)d_in[5];
    const float* cls_b  = (const float*)d_in[6];
    const float* reg_w  = (const float*)d_in[7];
    const float* reg_b  = (const float*)d_in[8];

    float* out     = (float*)d_out;
    float* emb     = out;                        // 1024*1024*49 = 51380224
    float* cls_out = out + 51380224;             // 1024*9
    float* reg_out = cls_out + 9216;             // 1024*36
    float* dbox    = reg_out + 36864;            // 2*100*4
    float* dsc     = dbox + 800;                 // 2*100
    float* dlab    = dsc + 200;                  // 2*100
    float* dval    = dlab + 200;                 // 2*100

    float* ws     = (float*)d_ws;
    float* h      = ws;                                      // 51380224 floats
    float* flat   = h + (size_t)N_IMG*C_MID*SP;              // 1048576
    float* pbox   = flat + (size_t)N_IMG*C_MID;              // 36864
    float* pscore = pbox + (size_t)N_IMG*9*4;                // 9216

    dim3 cgrid(NCOLS/BN, C_MID/BM);
    conv_gemm<0><<<cgrid, 256, 0, stream>>>(X, nullptr, w1, nullptr, h);
    conv_gemm<1><<<cgrid, 256, 0, stream>>>(X, h, w2, wd, emb);
    pool_kernel<<<N_IMG, 256, 0, stream>>>(emb, flat);
    head_kernel<<<N_IMG, 64, 0, stream>>>(flat, cls_w, cls_b, reg_w, reg_b, props,
                                          cls_out, reg_out, pbox, pscore);
    nms_kernel<<<2, 1024, 0, stream>>>(pbox, pscore, dbox, dsc, dlab, dval);
}

// Round 3
// 42766.800 us; speedup vs baseline: 5.0882x; 5.0882x over previous
//
#include <hip/hip_runtime.h>
#include <math.h>

#define N_IMG 1024
#define C_IN 512
#define C_MID 1024
#define HW 7
#define SP 49
#define NCOLS (N_IMG*SP)      /* 50176 */
#define K1 (C_IN*9)           /* 4608 */
#define K2 (C_MID*9 + C_IN)   /* 9728: conv2 + fused 1x1 shortcut */
#define BM 128
#define BN 128
#define BK 16

// ---------------------------------------------------------------------------
// Conv as implicit GEMM: C[oc, col] = sum_k A[oc,k] * im2col[k, col]
// MODE 0: A = w1 (K=4608), B from X, out = h = relu(conv1)
// MODE 1: A = [w2 | wd] (K=9728), B from [im2col(h) | X], out = embedded
// Grid (392, 8), 256 threads, 128x128 tile, 8x8 micro-tile as two 4-wide
// chunks at +0/+64: LDS reads are <=2-way bank aliasing (free on gfx950)
// instead of the 4-way conflicts of a contiguous 8-wide chunk.
// NOTE round-2 lesson: keep staging straight-line (no lambdas, no runtime
// buffer index, no launch_bounds min-wave arg) or the accumulator tile
// spills to scratch (~680 GB of HBM traffic, 5x regression).
// ---------------------------------------------------------------------------
template<int MODE>
__global__ __launch_bounds__(256)
void conv_gemm(const float* __restrict__ X, const float* __restrict__ Hin,
               const float* __restrict__ W, const float* __restrict__ WD,
               float* __restrict__ out)
{
    constexpr int K = MODE ? K2 : K1;
    __shared__ float As[BK][BM+4];
    __shared__ float Bs[BK][BN+4];

    const int tid = threadIdx.x;
    const int bn = blockIdx.x;
    const int bm = blockIdx.y;
    const int tx = tid & 15;
    const int ty = tid >> 4;

    // A-load: thread -> (row, 8 consecutive k)
    const int arow = tid >> 1;
    const int acol = (tid & 1) * 8;
    const int grow = bm*BM + arow;

    // B-load: thread -> k-row (tid>>4), cols (tid&15) + 16*jj (coalesced lanes)
    const int bk = tid >> 4;
    const int bc = tid & 15;
    int n8[8], iy8[8], ix8[8];
    #pragma unroll
    for (int jj = 0; jj < 8; jj++) {
        int col = bn*BN + bc + 16*jj;
        int n = col / SP;
        int p = col - n*SP;
        int y = p / HW;
        n8[jj] = n; iy8[jj] = y; ix8[jj] = p - y*HW;
    }

    float acc[8][8];
    #pragma unroll
    for (int i = 0; i < 8; i++)
        #pragma unroll
        for (int j = 0; j < 8; j++) acc[i][j] = 0.f;

    for (int k0 = 0; k0 < K; k0 += BK) {
        // ---- stage A tile (transposed into As[k][m]) ----
        {
            int kk = k0 + acol;
            const float* src;
            if (MODE == 0) {
                src = W + grow*K1 + kk;
            } else {
                src = (kk < C_MID*9) ? (W + grow*(C_MID*9) + kk)
                                     : (WD + grow*C_IN + (kk - C_MID*9));
            }
            float4 v0 = *(const float4*)(src);
            float4 v1 = *(const float4*)(src + 4);
            As[acol+0][arow] = v0.x; As[acol+1][arow] = v0.y;
            As[acol+2][arow] = v0.z; As[acol+3][arow] = v0.w;
            As[acol+4][arow] = v1.x; As[acol+5][arow] = v1.y;
            As[acol+6][arow] = v1.z; As[acol+7][arow] = v1.w;
        }
        // ---- stage B tile (im2col gather) ----
        {
            int k = k0 + bk;
            if (MODE == 0 || k < C_MID*9) {
                int c = k / 9;
                int r = k - c*9;
                int ky = r/3 - 1;
                int kx = (r - (r/3)*3) - 1;
                const float* SRC = (MODE == 0) ? X : Hin;
                const int CS = (MODE == 0) ? C_IN : C_MID;
                #pragma unroll
                for (int jj = 0; jj < 8; jj++) {
                    int iy = iy8[jj] + ky, ix = ix8[jj] + kx;
                    float v = 0.f;
                    if ((unsigned)iy < HW && (unsigned)ix < HW)
                        v = SRC[((n8[jj]*CS + c)*HW + iy)*HW + ix];
                    Bs[bk][bc + 16*jj] = v;
                }
            } else {
                int c = k - C_MID*9;
                #pragma unroll
                for (int jj = 0; jj < 8; jj++) {
                    Bs[bk][bc + 16*jj] =
                        X[((n8[jj]*C_IN + c)*HW + iy8[jj])*HW + ix8[jj]];
                }
            }
        }
        __syncthreads();
        #pragma unroll
        for (int kk = 0; kk < BK; kk++) {
            float a[8], b[8];
            *(float4*)&a[0] = *(const float4*)&As[kk][ty*4];
            *(float4*)&a[4] = *(const float4*)&As[kk][64 + ty*4];
            *(float4*)&b[0] = *(const float4*)&Bs[kk][tx*4];
            *(float4*)&b[4] = *(const float4*)&Bs[kk][64 + tx*4];
            #pragma unroll
            for (int i = 0; i < 8; i++)
                #pragma unroll
                for (int j = 0; j < 8; j++)
                    acc[i][j] = fmaf(a[i], b[j], acc[i][j]);
        }
        __syncthreads();
    }
    // ---- epilogue: relu + store NCHW (split 4+4 row/col mapping) ----
    #pragma unroll
    for (int j = 0; j < 8; j++) {
        int col = bn*BN + ((j < 4) ? tx*4 + j : 64 + tx*4 + (j-4));
        int n = col / SP;
        int p = col - n*SP;
        #pragma unroll
        for (int i = 0; i < 8; i++) {
            int m = bm*BM + ((i < 4) ? ty*4 + i : 64 + ty*4 + (i-4));
            out[(n*C_MID + m)*SP + p] = fmaxf(acc[i][j], 0.f);
        }
    }
}

// ---------------------------------------------------------------------------
__global__ __launch_bounds__(256)
void pool_kernel(const float* __restrict__ emb, float* __restrict__ flat)
{
    int n = blockIdx.x;
    for (int c = threadIdx.x; c < C_MID; c += 256) {
        const float* p = emb + (n*C_MID + c)*SP;
        float s = 0.f;
        #pragma unroll
        for (int i = 0; i < SP; i++) s += p[i];
        flat[n*C_MID + c] = s / 49.0f;
    }
}

// ---------------------------------------------------------------------------
// Per-image heads: 45 dot products (9 cls + 36 reg), softmax, box decode+clip.
// ---------------------------------------------------------------------------
__global__ __launch_bounds__(64)
void head_kernel(const float* __restrict__ flat,
                 const float* __restrict__ cls_w, const float* __restrict__ cls_b,
                 const float* __restrict__ reg_w, const float* __restrict__ reg_b,
                 const float* __restrict__ props,
                 float* __restrict__ cls_out, float* __restrict__ reg_out,
                 float* __restrict__ pbox, float* __restrict__ pscore)
{
    int n = blockIdx.x;
    __shared__ float f[C_MID];
    __shared__ float logits[9];
    __shared__ float regs[36];
    for (int c = threadIdx.x; c < C_MID; c += 64) f[c] = flat[n*C_MID + c];
    __syncthreads();
    int o = threadIdx.x;
    if (o < 45) {
        const float* w = (o < 9) ? (cls_w + o*C_MID) : (reg_w + (o-9)*C_MID);
        float a = (o < 9) ? cls_b[o] : reg_b[o-9];
        for (int c = 0; c < C_MID; c++) a = fmaf(f[c], w[c], a);
        if (o < 9) { cls_out[n*9 + o] = a; logits[o] = a; }
        else       { reg_out[n*36 + (o-9)] = a; regs[o-9] = a; }
    }
    __syncthreads();
    if (o < 9) {
        float m = logits[0];
        for (int i = 1; i < 9; i++) m = fmaxf(m, logits[i]);
        float se = 0.f;
        for (int i = 0; i < 9; i++) se += expf(logits[i] - m);
        pscore[n*9 + o] = expf(logits[o] - m) / se;
        {
            #pragma clang fp contract(off)
            float x1 = props[n*4+0], y1 = props[n*4+1];
            float x2 = props[n*4+2], y2 = props[n*4+3];
            float pw = x2 - x1, ph = y2 - y1;
            float pcx = x1 + 0.5f*pw, pcy = y1 + 0.5f*ph;
            float dx = regs[o*4+0] / 10.0f;
            float dy = regs[o*4+1] / 10.0f;
            float dw = fminf(regs[o*4+2] / 5.0f, 4.135166556742356f);
            float dh = fminf(regs[o*4+3] / 5.0f, 4.135166556742356f);
            float ncx = dx*pw + pcx, ncy = dy*ph + pcy;
            float nw = expf(dw)*pw,  nh = expf(dh)*ph;
            float bx1 = ncx - 0.5f*nw, by1 = ncy - 0.5f*nh;
            float bx2 = ncx + 0.5f*nw, by2 = ncy + 0.5f*nh;
            bx1 = fminf(fmaxf(bx1, 0.f), 640.f);
            by1 = fminf(fmaxf(by1, 0.f), 384.f);
            bx2 = fminf(fmaxf(bx2, 0.f), 640.f);
            by2 = fminf(fmaxf(by2, 0.f), 384.f);
            float* dst = pbox + (n*9 + o)*4;
            dst[0] = bx1; dst[1] = by1; dst[2] = bx2; dst[3] = by2;
        }
    }
}

// ---------------------------------------------------------------------------
// Per-image (2 blocks): candidate mask -> bitonic sort of 4096 (score desc,
// idx asc, matching lax.top_k ties) -> top-512 -> IoU bitmask (class-offset
// boxes, exact reference formula) -> serial greedy NMS -> first 100 kept.
// ---------------------------------------------------------------------------
__global__ __launch_bounds__(1024)
void nms_kernel(const float* __restrict__ pbox, const float* __restrict__ pscore,
                float* __restrict__ dbox, float* __restrict__ dsc,
                float* __restrict__ dlab, float* __restrict__ dval)
{
    #pragma clang fp contract(off)
    const int b = blockIdx.x;
    const int tid = threadIdx.x;
    __shared__ unsigned long long mbuf[4096];   // 32 KB: sort arrays, then masks
    __shared__ float s512[512];
    __shared__ int   id512[512];
    __shared__ float obx[512][4];
    __shared__ unsigned long long keepw[8];
    float* sc = (float*)mbuf;
    int*   si = (int*)(sc + 4096);
    const float NEG_INF = -__builtin_inff();

    for (int i = tid; i < 4096; i += 1024) {
        int p = i >> 3;
        int c = (i & 7) + 1;
        int n = b*512 + p;
        float s = pscore[n*9 + c];
        const float* bb = pbox + (n*9 + c)*4;
        float w = bb[2] - bb[0], h = bb[3] - bb[1];
        bool valid = (s > 0.05f) && (w >= 0.01f) && (h >= 0.01f);
        sc[i] = valid ? s : NEG_INF;
        si[i] = i;
    }
    __syncthreads();
    for (int k = 2; k <= 4096; k <<= 1) {
        for (int j = k >> 1; j > 0; j >>= 1) {
            for (int i = tid; i < 4096; i += 1024) {
                int ixj = i ^ j;
                if (ixj > i) {
                    float s1 = sc[i], s2 = sc[ixj];
                    int i1 = si[i], i2 = si[ixj];
                    bool before12 = (s1 > s2) || ((s1 == s2) && (i1 < i2));
                    bool up = ((i & k) == 0);
                    if (up ? !before12 : before12) {
                        sc[i] = s2; sc[ixj] = s1;
                        si[i] = i2; si[ixj] = i1;
                    }
                }
            }
            __syncthreads();
        }
    }
    if (tid < 512) {
        float s = sc[tid];
        int id = si[tid];
        s512[tid] = s;
        id512[tid] = id;
        int c = (id & 7) + 1;
        int n = b*512 + (id >> 3);
        float off = (float)c * 641.0f;   // (max(H,W)+1) * label
        const float* bb = pbox + (n*9 + c)*4;
        obx[tid][0] = bb[0] + off;
        obx[tid][1] = bb[1] + off;
        obx[tid][2] = bb[2] + off;
        obx[tid][3] = bb[3] + off;
    }
    __syncthreads();
    unsigned long long* mask = mbuf;   // [512][8]
    for (int idx = tid; idx < 4096; idx += 1024) {
        int i = idx >> 3, w = idx & 7;
        float ax1 = obx[i][0], ay1 = obx[i][1], ax2 = obx[i][2], ay2 = obx[i][3];
        float aarea = (ax2 - ax1) * (ay2 - ay1);
        unsigned long long m = 0;
        int j0 = w << 6;
        for (int jj = 0; jj < 64; jj++) {
            int j = j0 + jj;
            if (j > i) {
                float bx1 = obx[j][0], by1 = obx[j][1];
                float bx2 = obx[j][2], by2 = obx[j][3];
                float barea = (bx2 - bx1) * (by2 - by1);
                float lx = fmaxf(ax1, bx1), ly = fmaxf(ay1, by1);
                float rx = fminf(ax2, bx2), ry = fminf(ay2, by2);
                float iw = fmaxf(rx - lx, 0.f), ih = fmaxf(ry - ly, 0.f);
                float inter = iw * ih;
                float iou = inter / fmaxf(aarea + barea - inter, 1e-8f);
                if (iou > 0.5f) m |= (1ull << jj);
            }
        }
        mask[(i << 3) + w] = m;
    }
    if (tid < 8) {
        unsigned long long kw = 0;
        for (int jj = 0; jj < 64; jj++)
            if (s512[(tid << 6) + jj] != NEG_INF) kw |= (1ull << jj);
        keepw[tid] = kw;
    }
    __syncthreads();
    if (tid == 0) {
        for (int i = 0; i < 512; i++) {
            if ((keepw[i >> 6] >> (i & 63)) & 1ull) {
                const unsigned long long* mi = mask + (i << 3);
                #pragma unroll
                for (int w = 0; w < 8; w++) keepw[w] &= ~mi[w];
            }
        }
        int cnt = 0;
        for (int i = 0; i < 512 && cnt < 100; i++) {
            if ((keepw[i >> 6] >> (i & 63)) & 1ull) {
                int id = id512[i];
                int c = (id & 7) + 1;
                int n = b*512 + (id >> 3);
                const float* bb = pbox + (n*9 + c)*4;
                float* db = dbox + (b*100 + cnt)*4;
                db[0] = bb[0]; db[1] = bb[1]; db[2] = bb[2]; db[3] = bb[3];
                dsc[b*100 + cnt] = s512[i];
                dlab[b*100 + cnt] = (float)c;
                dval[b*100 + cnt] = 1.0f;
                cnt++;
            }
        }
        for (; cnt < 100; cnt++) {
            float* db = dbox + (b*100 + cnt)*4;
            db[0] = 0.f; db[1] = 0.f; db[2] = 0.f; db[3] = 0.f;
            dsc[b*100 + cnt] = 0.f;
            dlab[b*100 + cnt] = 0.f;
            dval[b*100 + cnt] = 0.f;
        }
    }
}

// ---------------------------------------------------------------------------
extern "C" void kernel_launch(void* const* d_in, const int* in_sizes, int n_in,
                              void* d_out, int out_size, void* d_ws, size_t ws_size,
                              hipStream_t stream)
{
    const float* X      = (const float*)d_in[0];
    const float* props  = (const float*)d_in[1];
    const float* w1     = (const float*)d_in[2];
    const float* w2     = (const float*)d_in[3];
    const float* wd     = (const float*)d_in[4];
    const float* cls_w  = (const float*)d_in[5];
    const float* cls_b  = (const float*)d_in[6];
    const float* reg_w  = (const float*)d_in[7];
    const float* reg_b  = (const float*)d_in[8];

    float* out     = (float*)d_out;
    float* emb     = out;                        // 1024*1024*49 = 51380224
    float* cls_out = out + 51380224;             // 1024*9
    float* reg_out = cls_out + 9216;             // 1024*36
    float* dbox    = reg_out + 36864;            // 2*100*4
    float* dsc     = dbox + 800;                 // 2*100
    float* dlab    = dsc + 200;                  // 2*100
    float* dval    = dlab + 200;                 // 2*100

    float* ws     = (float*)d_ws;
    float* h      = ws;                                      // 51380224 floats
    float* flat   = h + (size_t)N_IMG*C_MID*SP;              // 1048576
    float* pbox   = flat + (size_t)N_IMG*C_MID;              // 36864
    float* pscore = pbox + (size_t)N_IMG*9*4;                // 9216

    dim3 cgrid(NCOLS/BN, C_MID/BM);
    conv_gemm<0><<<cgrid, 256, 0, stream>>>(X, nullptr, w1, nullptr, h);
    conv_gemm<1><<<cgrid, 256, 0, stream>>>(X, h, w2, wd, emb);
    pool_kernel<<<N_IMG, 256, 0, stream>>>(emb, flat);
    head_kernel<<<N_IMG, 64, 0, stream>>>(flat, cls_w, cls_b, reg_w, reg_b, props,
                                          cls_out, reg_out, pbox, pscore);
    nms_kernel<<<2, 1024, 0, stream>>>(pbox, pscore, dbox, dsc, dlab, dval);
}

// Round 4
// 11363.574 us; speedup vs baseline: 19.1496x; 3.7635x over previous
//
#include <hip/hip_runtime.h>
#include <math.h>

#define N_IMG 1024
#define C_IN 512
#define C_MID 1024
#define HW 7
#define SP 49
#define NCOLS (N_IMG*SP)      /* 50176 */
#define K1 (C_IN*9)           /* 4608 */
#define K2 (C_MID*9 + C_IN)   /* 9728: conv2 + fused 1x1 shortcut */
#define LDSROW 40             /* 32 k + 8 pad (ushorts); 80 B row, 16 B aligned */

typedef short bf16x8 __attribute__((ext_vector_type(8)));
typedef float f32x4  __attribute__((ext_vector_type(4)));

// RNE fp32 -> (hi bf16, lo bf16) packed as lo<<16 | hi.
__device__ __forceinline__ unsigned splitpack(float v) {
    unsigned u  = __float_as_uint(v);
    unsigned hi = (u + 0x7FFFu + ((u >> 16) & 1u)) >> 16;
    float hf    = __uint_as_float(hi << 16);
    float d     = v - hf;                       // exact (Sterbenz)
    unsigned ud = __float_as_uint(d);
    unsigned lo = (ud + 0x7FFFu + ((ud >> 16) & 1u)) >> 16;
    return (hi & 0xFFFFu) | (lo << 16);
}

// ---------------------------------------------------------------------------
// Conv as implicit GEMM on MFMA, split-bf16 (3-product fp32 emulation).
// MODE 0: A = w1 (K=4608), B = im2col(X),       out = h packed hi/lo uint
// MODE 1: A = [w2|wd] (K=9728), B = [im2col(h_packed) | X], out = emb fp32
// Grid (392,8), 256 thr = 4 waves; block tile 128x128; wave tile 64x64
// = 4x4 MFMA 16x16x32 tiles; BK=32; As/Bs stored [row|col][k] row-pad 40.
// Straight-line staging (round-2 lesson: lambdas/dbuf => acc spill).
// ---------------------------------------------------------------------------
template<int MODE>
__global__ __launch_bounds__(256)
void conv_mfma(const float* __restrict__ X, const unsigned* __restrict__ Hc,
               const float* __restrict__ W, const float* __restrict__ WD,
               float* __restrict__ outF, unsigned* __restrict__ outU)
{
    constexpr int K = MODE ? K2 : K1;
    __shared__ unsigned short As_hi[128*LDSROW];
    __shared__ unsigned short As_lo[128*LDSROW];
    __shared__ unsigned short Bs_hi[128*LDSROW];
    __shared__ unsigned short Bs_lo[128*LDSROW];

    const int tid = threadIdx.x;
    const int bn = blockIdx.x, bm = blockIdx.y;

    const int ln = tid & 63;
    const int wv = tid >> 6;
    const int lm = ln & 15, lq = ln >> 4;
    const int wm = (wv & 1) * 64;         // wave m-origin in tile
    const int wn = (wv >> 1) * 64;        // wave n-origin in tile
    const int koff = lq * 8;              // k offset of this lane's fragment

    // A staging: thread covers rows {arow, +32, +64, +96}, 4 consecutive k at ak
    const int arow = tid >> 3;
    const int ak = (tid & 7) * 4;

    // B staging: thread covers one col, 16 consecutive k at bk0
    const int bcol = tid >> 1;
    const int bk0 = (tid & 1) * 16;
    const int col = bn*128 + bcol;
    const int bnimg = col / SP;
    const int bp = col - bnimg*SP;
    const int biy = bp / HW;
    const int bix = bp - biy*HW;

    f32x4 acc[4][4];
    #pragma unroll
    for (int i = 0; i < 4; i++)
        #pragma unroll
        for (int j = 0; j < 4; j++)
            acc[i][j] = (f32x4){0.f, 0.f, 0.f, 0.f};

    for (int kc = 0; kc < K; kc += 32) {
        // ---- stage A (weights), coalesced float4, split on the fly ----
        #pragma unroll
        for (int g = 0; g < 4; g++) {
            const int row = arow + g*32;
            const int grow = bm*128 + row;
            const int kk = kc + ak;
            const float* src;
            if (MODE == 0) {
                src = W + (size_t)grow*K1 + kk;
            } else {
                src = (kk < C_MID*9) ? (W + (size_t)grow*(C_MID*9) + kk)
                                     : (WD + (size_t)grow*C_IN + (kk - C_MID*9));
            }
            float4 v = *(const float4*)src;
            unsigned p0 = splitpack(v.x), p1 = splitpack(v.y);
            unsigned p2 = splitpack(v.z), p3 = splitpack(v.w);
            uint2 wh, wl;
            wh.x = (p0 & 0xFFFFu) | (p1 << 16);
            wh.y = (p2 & 0xFFFFu) | (p3 << 16);
            wl.x = (p0 >> 16) | (p1 & 0xFFFF0000u);
            wl.y = (p2 >> 16) | (p3 & 0xFFFF0000u);
            *(uint2*)&As_hi[row*LDSROW + ak] = wh;
            *(uint2*)&As_lo[row*LDSROW + ak] = wl;
        }
        // ---- stage B (im2col gather) ----
        {
            unsigned hp[8], lp[8];
            unsigned prev = 0;
            #pragma unroll
            for (int e = 0; e < 16; e++) {
                const int k = kc + bk0 + e;
                unsigned p;
                if (MODE == 1 && k < C_MID*9) {
                    int c = k / 9;
                    int r = k - c*9;
                    int t3 = r / 3;
                    int iy = biy + t3 - 1;
                    int ix = bix + (r - t3*3) - 1;
                    p = 0;
                    if ((unsigned)iy < HW && (unsigned)ix < HW)
                        p = Hc[((size_t)(bnimg*C_MID + c)*HW + iy)*HW + ix];
                } else if (MODE == 1) {
                    int c = k - C_MID*9;
                    float v = X[((size_t)(bnimg*C_IN + c)*HW + biy)*HW + bix];
                    p = splitpack(v);
                } else {
                    int c = k / 9;
                    int r = k - c*9;
                    int t3 = r / 3;
                    int iy = biy + t3 - 1;
                    int ix = bix + (r - t3*3) - 1;
                    float v = 0.f;
                    if ((unsigned)iy < HW && (unsigned)ix < HW)
                        v = X[((size_t)(bnimg*C_IN + c)*HW + iy)*HW + ix];
                    p = splitpack(v);
                }
                if ((e & 1) == 0) {
                    prev = p;
                } else {
                    hp[e >> 1] = (prev & 0xFFFFu) | (p << 16);
                    lp[e >> 1] = (prev >> 16) | (p & 0xFFFF0000u);
                }
            }
            uint4 w0, w1;
            w0.x = hp[0]; w0.y = hp[1]; w0.z = hp[2]; w0.w = hp[3];
            w1.x = hp[4]; w1.y = hp[5]; w1.z = hp[6]; w1.w = hp[7];
            *(uint4*)&Bs_hi[bcol*LDSROW + bk0] = w0;
            *(uint4*)&Bs_hi[bcol*LDSROW + bk0 + 8] = w1;
            w0.x = lp[0]; w0.y = lp[1]; w0.z = lp[2]; w0.w = lp[3];
            w1.x = lp[4]; w1.y = lp[5]; w1.z = lp[6]; w1.w = lp[7];
            *(uint4*)&Bs_lo[bcol*LDSROW + bk0] = w0;
            *(uint4*)&Bs_lo[bcol*LDSROW + bk0 + 8] = w1;
        }
        __syncthreads();
        // ---- fragments + 48 MFMA (hi*hi, lo*hi, hi*lo) ----
        {
            bf16x8 ah[4], bh[4], al[4], bl[4];
            #pragma unroll
            for (int i = 0; i < 4; i++)
                ah[i] = *(const bf16x8*)&As_hi[(wm + i*16 + lm)*LDSROW + koff];
            #pragma unroll
            for (int j = 0; j < 4; j++)
                bh[j] = *(const bf16x8*)&Bs_hi[(wn + j*16 + lm)*LDSROW + koff];
            #pragma unroll
            for (int i = 0; i < 4; i++)
                #pragma unroll
                for (int j = 0; j < 4; j++)
                    acc[i][j] = __builtin_amdgcn_mfma_f32_16x16x32_bf16(
                        ah[i], bh[j], acc[i][j], 0, 0, 0);
            #pragma unroll
            for (int i = 0; i < 4; i++)
                al[i] = *(const bf16x8*)&As_lo[(wm + i*16 + lm)*LDSROW + koff];
            #pragma unroll
            for (int i = 0; i < 4; i++)
                #pragma unroll
                for (int j = 0; j < 4; j++)
                    acc[i][j] = __builtin_amdgcn_mfma_f32_16x16x32_bf16(
                        al[i], bh[j], acc[i][j], 0, 0, 0);
            #pragma unroll
            for (int j = 0; j < 4; j++)
                bl[j] = *(const bf16x8*)&Bs_lo[(wn + j*16 + lm)*LDSROW + koff];
            #pragma unroll
            for (int i = 0; i < 4; i++)
                #pragma unroll
                for (int j = 0; j < 4; j++)
                    acc[i][j] = __builtin_amdgcn_mfma_f32_16x16x32_bf16(
                        ah[i], bl[j], acc[i][j], 0, 0, 0);
        }
        __syncthreads();
    }

    // ---- epilogue: relu; MODE0 packs h as hi/lo uint, MODE1 stores fp32 ----
    // C/D layout (m89-verified): col = lane&15, row = (lane>>4)*4 + reg.
    #pragma unroll
    for (int j = 0; j < 4; j++) {
        const int gc = bn*128 + wn + j*16 + lm;
        const int n = gc / SP;
        const int p = gc - n*SP;
        #pragma unroll
        for (int i = 0; i < 4; i++) {
            #pragma unroll
            for (int r = 0; r < 4; r++) {
                const int m = bm*128 + wm + i*16 + lq*4 + r;
                float val = fmaxf(acc[i][j][r], 0.f);
                if (MODE == 0)
                    outU[((size_t)n*C_MID + m)*SP + p] = splitpack(val);
                else
                    outF[((size_t)n*C_MID + m)*SP + p] = val;
            }
        }
    }
}

// ---------------------------------------------------------------------------
__global__ __launch_bounds__(256)
void pool_kernel(const float* __restrict__ emb, float* __restrict__ flat)
{
    int n = blockIdx.x;
    for (int c = threadIdx.x; c < C_MID; c += 256) {
        const float* p = emb + ((size_t)n*C_MID + c)*SP;
        float s = 0.f;
        #pragma unroll
        for (int i = 0; i < SP; i++) s += p[i];
        flat[n*C_MID + c] = s / 49.0f;
    }
}

// ---------------------------------------------------------------------------
// Per-image heads: 45 dot products (9 cls + 36 reg), softmax, box decode+clip.
// ---------------------------------------------------------------------------
__global__ __launch_bounds__(64)
void head_kernel(const float* __restrict__ flat,
                 const float* __restrict__ cls_w, const float* __restrict__ cls_b,
                 const float* __restrict__ reg_w, const float* __restrict__ reg_b,
                 const float* __restrict__ props,
                 float* __restrict__ cls_out, float* __restrict__ reg_out,
                 float* __restrict__ pbox, float* __restrict__ pscore)
{
    int n = blockIdx.x;
    __shared__ float f[C_MID];
    __shared__ float logits[9];
    __shared__ float regs[36];
    for (int c = threadIdx.x; c < C_MID; c += 64) f[c] = flat[n*C_MID + c];
    __syncthreads();
    int o = threadIdx.x;
    if (o < 45) {
        const float* w = (o < 9) ? (cls_w + o*C_MID) : (reg_w + (o-9)*C_MID);
        float a = (o < 9) ? cls_b[o] : reg_b[o-9];
        for (int c = 0; c < C_MID; c++) a = fmaf(f[c], w[c], a);
        if (o < 9) { cls_out[n*9 + o] = a; logits[o] = a; }
        else       { reg_out[n*36 + (o-9)] = a; regs[o-9] = a; }
    }
    __syncthreads();
    if (o < 9) {
        float m = logits[0];
        for (int i = 1; i < 9; i++) m = fmaxf(m, logits[i]);
        float se = 0.f;
        for (int i = 0; i < 9; i++) se += expf(logits[i] - m);
        pscore[n*9 + o] = expf(logits[o] - m) / se;
        {
            #pragma clang fp contract(off)
            float x1 = props[n*4+0], y1 = props[n*4+1];
            float x2 = props[n*4+2], y2 = props[n*4+3];
            float pw = x2 - x1, ph = y2 - y1;
            float pcx = x1 + 0.5f*pw, pcy = y1 + 0.5f*ph;
            float dx = regs[o*4+0] / 10.0f;
            float dy = regs[o*4+1] / 10.0f;
            float dw = fminf(regs[o*4+2] / 5.0f, 4.135166556742356f);
            float dh = fminf(regs[o*4+3] / 5.0f, 4.135166556742356f);
            float ncx = dx*pw + pcx, ncy = dy*ph + pcy;
            float nw = expf(dw)*pw,  nh = expf(dh)*ph;
            float bx1 = ncx - 0.5f*nw, by1 = ncy - 0.5f*nh;
            float bx2 = ncx + 0.5f*nw, by2 = ncy + 0.5f*nh;
            bx1 = fminf(fmaxf(bx1, 0.f), 640.f);
            by1 = fminf(fmaxf(by1, 0.f), 384.f);
            bx2 = fminf(fmaxf(bx2, 0.f), 640.f);
            by2 = fminf(fmaxf(by2, 0.f), 384.f);
            float* dst = pbox + (n*9 + o)*4;
            dst[0] = bx1; dst[1] = by1; dst[2] = bx2; dst[3] = by2;
        }
    }
}

// ---------------------------------------------------------------------------
// Per-image (2 blocks): candidate mask -> bitonic sort of 4096 (score desc,
// idx asc, matching lax.top_k ties) -> top-512 -> IoU bitmask (class-offset
// boxes, exact reference formula) -> serial greedy NMS -> first 100 kept.
// ---------------------------------------------------------------------------
__global__ __launch_bounds__(1024)
void nms_kernel(const float* __restrict__ pbox, const float* __restrict__ pscore,
                float* __restrict__ dbox, float* __restrict__ dsc,
                float* __restrict__ dlab, float* __restrict__ dval)
{
    #pragma clang fp contract(off)
    const int b = blockIdx.x;
    const int tid = threadIdx.x;
    __shared__ unsigned long long mbuf[4096];   // 32 KB: sort arrays, then masks
    __shared__ float s512[512];
    __shared__ int   id512[512];
    __shared__ float obx[512][4];
    __shared__ unsigned long long keepw[8];
    float* sc = (float*)mbuf;
    int*   si = (int*)(sc + 4096);
    const float NEG_INF = -__builtin_inff();

    for (int i = tid; i < 4096; i += 1024) {
        int p = i >> 3;
        int c = (i & 7) + 1;
        int n = b*512 + p;
        float s = pscore[n*9 + c];
        const float* bb = pbox + (n*9 + c)*4;
        float w = bb[2] - bb[0], h = bb[3] - bb[1];
        bool valid = (s > 0.05f) && (w >= 0.01f) && (h >= 0.01f);
        sc[i] = valid ? s : NEG_INF;
        si[i] = i;
    }
    __syncthreads();
    for (int k = 2; k <= 4096; k <<= 1) {
        for (int j = k >> 1; j > 0; j >>= 1) {
            for (int i = tid; i < 4096; i += 1024) {
                int ixj = i ^ j;
                if (ixj > i) {
                    float s1 = sc[i], s2 = sc[ixj];
                    int i1 = si[i], i2 = si[ixj];
                    bool before12 = (s1 > s2) || ((s1 == s2) && (i1 < i2));
                    bool up = ((i & k) == 0);
                    if (up ? !before12 : before12) {
                        sc[i] = s2; sc[ixj] = s1;
                        si[i] = i2; si[ixj] = i1;
                    }
                }
            }
            __syncthreads();
        }
    }
    if (tid < 512) {
        float s = sc[tid];
        int id = si[tid];
        s512[tid] = s;
        id512[tid] = id;
        int c = (id & 7) + 1;
        int n = b*512 + (id >> 3);
        float off = (float)c * 641.0f;   // (max(H,W)+1) * label
        const float* bb = pbox + (n*9 + c)*4;
        obx[tid][0] = bb[0] + off;
        obx[tid][1] = bb[1] + off;
        obx[tid][2] = bb[2] + off;
        obx[tid][3] = bb[3] + off;
    }
    __syncthreads();
    unsigned long long* mask = mbuf;   // [512][8]
    for (int idx = tid; idx < 4096; idx += 1024) {
        int i = idx >> 3, w = idx & 7;
        float ax1 = obx[i][0], ay1 = obx[i][1], ax2 = obx[i][2], ay2 = obx[i][3];
        float aarea = (ax2 - ax1) * (ay2 - ay1);
        unsigned long long m = 0;
        int j0 = w << 6;
        for (int jj = 0; jj < 64; jj++) {
            int j = j0 + jj;
            if (j > i) {
                float bx1 = obx[j][0], by1 = obx[j][1];
                float bx2 = obx[j][2], by2 = obx[j][3];
                float barea = (bx2 - bx1) * (by2 - by1);
                float lx = fmaxf(ax1, bx1), ly = fmaxf(ay1, by1);
                float rx = fminf(ax2, bx2), ry = fminf(ay2, by2);
                float iw = fmaxf(rx - lx, 0.f), ih = fmaxf(ry - ly, 0.f);
                float inter = iw * ih;
                float iou = inter / fmaxf(aarea + barea - inter, 1e-8f);
                if (iou > 0.5f) m |= (1ull << jj);
            }
        }
        mask[(i << 3) + w] = m;
    }
    if (tid < 8) {
        unsigned long long kw = 0;
        for (int jj = 0; jj < 64; jj++)
            if (s512[(tid << 6) + jj] != NEG_INF) kw |= (1ull << jj);
        keepw[tid] = kw;
    }
    __syncthreads();
    if (tid == 0) {
        for (int i = 0; i < 512; i++) {
            if ((keepw[i >> 6] >> (i & 63)) & 1ull) {
                const unsigned long long* mi = mask + (i << 3);
                #pragma unroll
                for (int w = 0; w < 8; w++) keepw[w] &= ~mi[w];
            }
        }
        int cnt = 0;
        for (int i = 0; i < 512 && cnt < 100; i++) {
            if ((keepw[i >> 6] >> (i & 63)) & 1ull) {
                int id = id512[i];
                int c = (id & 7) + 1;
                int n = b*512 + (id >> 3);
                const float* bb = pbox + (n*9 + c)*4;
                float* db = dbox + (b*100 + cnt)*4;
                db[0] = bb[0]; db[1] = bb[1]; db[2] = bb[2]; db[3] = bb[3];
                dsc[b*100 + cnt] = s512[i];
                dlab[b*100 + cnt] = (float)c;
                dval[b*100 + cnt] = 1.0f;
                cnt++;
            }
        }
        for (; cnt < 100; cnt++) {
            float* db = dbox + (b*100 + cnt)*4;
            db[0] = 0.f; db[1] = 0.f; db[2] = 0.f; db[3] = 0.f;
            dsc[b*100 + cnt] = 0.f;
            dlab[b*100 + cnt] = 0.f;
            dval[b*100 + cnt] = 0.f;
        }
    }
}

// ---------------------------------------------------------------------------
extern "C" void kernel_launch(void* const* d_in, const int* in_sizes, int n_in,
                              void* d_out, int out_size, void* d_ws, size_t ws_size,
                              hipStream_t stream)
{
    const float* X      = (const float*)d_in[0];
    const float* props  = (const float*)d_in[1];
    const float* w1     = (const float*)d_in[2];
    const float* w2     = (const float*)d_in[3];
    const float* wd     = (const float*)d_in[4];
    const float* cls_w  = (const float*)d_in[5];
    const float* cls_b  = (const float*)d_in[6];
    const float* reg_w  = (const float*)d_in[7];
    const float* reg_b  = (const float*)d_in[8];

    float* out     = (float*)d_out;
    float* emb     = out;                        // 1024*1024*49 = 51380224
    float* cls_out = out + 51380224;             // 1024*9
    float* reg_out = cls_out + 9216;             // 1024*36
    float* dbox    = reg_out + 36864;            // 2*100*4
    float* dsc     = dbox + 800;                 // 2*100
    float* dlab    = dsc + 200;                  // 2*100
    float* dval    = dlab + 200;                 // 2*100

    float* ws      = (float*)d_ws;
    unsigned* h_u  = (unsigned*)ws;                          // 51380224 uints (packed hi/lo bf16)
    float* flat    = ws + (size_t)N_IMG*C_MID*SP;            // 1048576
    float* pbox    = flat + (size_t)N_IMG*C_MID;             // 36864
    float* pscore  = pbox + (size_t)N_IMG*9*4;               // 9216

    dim3 cgrid(NCOLS/128, C_MID/128);
    conv_mfma<0><<<cgrid, 256, 0, stream>>>(X, nullptr, w1, nullptr, nullptr, h_u);
    conv_mfma<1><<<cgrid, 256, 0, stream>>>(X, h_u, w2, wd, emb, nullptr);
    pool_kernel<<<N_IMG, 256, 0, stream>>>(emb, flat);
    head_kernel<<<N_IMG, 64, 0, stream>>>(flat, cls_w, cls_b, reg_w, reg_b, props,
                                          cls_out, reg_out, pbox, pscore);
    nms_kernel<<<2, 1024, 0, stream>>>(pbox, pscore, dbox, dsc, dlab, dval);
}

// Round 5
// 5950.710 us; speedup vs baseline: 36.5684x; 1.9096x over previous
//
#include <hip/hip_runtime.h>
#include <math.h>

#define N_IMG 1024
#define C_IN 512
#define C_MID 1024
#define HW 7
#define SP 49
#define NCOLS (N_IMG*SP)      /* 50176 */
#define LDSROW 40             /* 32 k + 8 pad (ushorts); 80 B row */

typedef short bf16x8 __attribute__((ext_vector_type(8)));
typedef float f32x4  __attribute__((ext_vector_type(4)));

// RNE fp32 -> (hi bf16, lo bf16) packed as lo<<16 | hi.
__device__ __forceinline__ unsigned splitpack(float v) {
    unsigned u  = __float_as_uint(v);
    unsigned hi = (u + 0x7FFFu + ((u >> 16) & 1u)) >> 16;
    float hf    = __uint_as_float(hi << 16);
    float d     = v - hf;                       // exact (Sterbenz)
    unsigned ud = __float_as_uint(d);
    unsigned lo = (ud + 0x7FFFu + ((ud >> 16) & 1u)) >> 16;
    return (hi & 0xFFFFu) | (lo << 16);
}

// ---------------------------------------------------------------------------
// Pre-pass: split X into packed hi|lo uints (same [n][c][p] layout).
__global__ __launch_bounds__(256)
void pack_x(const float* __restrict__ X, unsigned* __restrict__ Xpk)
{
    int i = blockIdx.x*256 + threadIdx.x;      // grid sized exactly
    Xpk[i] = splitpack(X[i]);
}

// Pre-pass: tile-order weight packs, separate hi/lo ushort arrays.
// Layout: [r][cc][bm][oc'(128)][c'(32)], each tile 4096 ushorts.
__global__ __launch_bounds__(256)
void pack_w1(const float* __restrict__ w, unsigned short* __restrict__ Wh,
             unsigned short* __restrict__ Wl)
{
    int e = blockIdx.x*256 + threadIdx.x;      // < 4718592
    int cp = e & 31, oc = (e>>5)&127, bm = (e>>12)&7, cc = (e>>15)&15, r = e>>19;
    float v = w[((size_t)(bm*128+oc)*512 + (cc*32+cp))*9 + r];
    unsigned pk = splitpack(v);
    Wh[e] = (unsigned short)(pk & 0xFFFFu);
    Wl[e] = (unsigned short)(pk >> 16);
}
__global__ __launch_bounds__(256)
void pack_w2(const float* __restrict__ w, unsigned short* __restrict__ Wh,
             unsigned short* __restrict__ Wl)
{
    int e = blockIdx.x*256 + threadIdx.x;      // < 9437184
    int cp = e & 31, oc = (e>>5)&127, bm = (e>>12)&7, cc = (e>>15)&31, r = e>>20;
    float v = w[((size_t)(bm*128+oc)*1024 + (cc*32+cp))*9 + r];
    unsigned pk = splitpack(v);
    Wh[e] = (unsigned short)(pk & 0xFFFFu);
    Wl[e] = (unsigned short)(pk >> 16);
}
__global__ __launch_bounds__(256)
void pack_wd(const float* __restrict__ w, unsigned short* __restrict__ Wh,
             unsigned short* __restrict__ Wl)
{
    int e = blockIdx.x*256 + threadIdx.x;      // < 524288
    int cp = e & 31, oc = (e>>5)&127, bm = (e>>12)&7, cc = e>>15;
    float v = w[(size_t)(bm*128+oc)*512 + cc*32+cp];
    unsigned pk = splitpack(v);
    Wh[e] = (unsigned short)(pk & 0xFFFFu);
    Wl[e] = (unsigned short)(pk >> 16);
}

// ---------------------------------------------------------------------------
// Tap-major conv GEMM on MFMA, split-bf16 (3-product fp32 emulation).
// For each tap r (9) and 32-channel chunk: A tile from pre-packed weights
// (pure coalesced copies), B tile = packed input, per-column shift pp=p+off(r),
// validity per (column,tap) computed ONCE. MODE1 adds 16 shortcut chunks
// (1x1 conv over raw X, split in-kernel - only 5% of chunks).
// Grid (392,8), 256 thr = 4 waves, 128x128 block tile, 4x4 MFMA 16x16x32/wave.
// ---------------------------------------------------------------------------
template<int MODE>
__global__ __launch_bounds__(256)
void conv_mfma(const unsigned* __restrict__ Bpk,   // packed [n][CS][49]
               const float* __restrict__ Xf,       // raw X (MODE1 shortcut)
               const unsigned short* __restrict__ Wh,
               const unsigned short* __restrict__ Wl,
               const unsigned short* __restrict__ Dh,
               const unsigned short* __restrict__ Dl,
               float* __restrict__ outF, unsigned* __restrict__ outU)
{
    constexpr int CS  = MODE ? C_MID : C_IN;
    constexpr int NCC = MODE ? 32 : 16;
    __shared__ unsigned short As_hi[128*LDSROW];
    __shared__ unsigned short As_lo[128*LDSROW];
    __shared__ unsigned short Bs_hi[128*LDSROW];
    __shared__ unsigned short Bs_lo[128*LDSROW];

    const int tid = threadIdx.x;
    const int bn = blockIdx.x, bm = blockIdx.y;

    const int ln = tid & 63;
    const int wv = tid >> 6;
    const int lm = ln & 15, lq = ln >> 4;
    const int wm = (wv & 1) * 64;
    const int wn = (wv >> 1) * 64;
    const int koff = lq * 8;

    // A staging: thread -> 16 consecutive ushorts at tile offset tid*16
    const int aoff = (tid >> 1)*LDSROW + (tid & 1)*16;
    // B staging: thread -> one column, 16 consecutive channels
    const int bcol = tid >> 1;
    const int half16 = (tid & 1) * 16;
    const int col = bn*128 + bcol;
    const int bnimg = col / SP;
    const int bp = col - bnimg*SP;
    const int by = bp / HW;
    const int bx = bp - by*HW;
    const int bo = bcol*LDSROW + half16;

    f32x4 acc[4][4];
    #pragma unroll
    for (int i = 0; i < 4; i++)
        #pragma unroll
        for (int j = 0; j < 4; j++)
            acc[i][j] = (f32x4){0.f, 0.f, 0.f, 0.f};

    for (int r = 0; r < 9; ++r) {
        const int t3 = r / 3;
        const int dy = t3 - 1;
        const int dx = (r - t3*3) - 1;
        const bool valid = ((unsigned)(by + dy) < (unsigned)HW) &&
                           ((unsigned)(bx + dx) < (unsigned)HW);
        const int pp = bp + dy*HW + dx;
        for (int cc = 0; cc < NCC; ++cc) {
            // ---- A stage: pure copy from tile-ordered pack ----
            {
                const size_t tb = ((size_t)((r*NCC + cc)*8 + bm) << 12) + tid*16;
                uint4 h0 = *(const uint4*)(Wh + tb);
                uint4 h1 = *(const uint4*)(Wh + tb + 8);
                uint4 l0 = *(const uint4*)(Wl + tb);
                uint4 l1 = *(const uint4*)(Wl + tb + 8);
                *(uint4*)&As_hi[aoff]     = h0;
                *(uint4*)&As_hi[aoff + 8] = h1;
                *(uint4*)&As_lo[aoff]     = l0;
                *(uint4*)&As_lo[aoff + 8] = l1;
            }
            // ---- B stage: shifted packed loads, imm offsets ----
            {
                unsigned v[16];
                if (valid) {
                    const unsigned* src =
                        Bpk + ((size_t)bnimg*CS + cc*32 + half16)*SP + pp;
                    #pragma unroll
                    for (int e = 0; e < 16; ++e) v[e] = src[e*SP];
                } else {
                    #pragma unroll
                    for (int e = 0; e < 16; ++e) v[e] = 0u;
                }
                unsigned hp[8], lp[8];
                #pragma unroll
                for (int j2 = 0; j2 < 8; ++j2) {
                    unsigned p0 = v[2*j2], p1 = v[2*j2+1];
                    hp[j2] = (p0 & 0xFFFFu) | (p1 << 16);
                    lp[j2] = (p0 >> 16) | (p1 & 0xFFFF0000u);
                }
                *(uint4*)&Bs_hi[bo]     = *(uint4*)&hp[0];
                *(uint4*)&Bs_hi[bo + 8] = *(uint4*)&hp[4];
                *(uint4*)&Bs_lo[bo]     = *(uint4*)&lp[0];
                *(uint4*)&Bs_lo[bo + 8] = *(uint4*)&lp[4];
            }
            __syncthreads();
            {
                bf16x8 ah[4], bh[4], al[4], bl[4];
                #pragma unroll
                for (int i = 0; i < 4; i++)
                    ah[i] = *(const bf16x8*)&As_hi[(wm + i*16 + lm)*LDSROW + koff];
                #pragma unroll
                for (int j = 0; j < 4; j++)
                    bh[j] = *(const bf16x8*)&Bs_hi[(wn + j*16 + lm)*LDSROW + koff];
                #pragma unroll
                for (int i = 0; i < 4; i++)
                    #pragma unroll
                    for (int j = 0; j < 4; j++)
                        acc[i][j] = __builtin_amdgcn_mfma_f32_16x16x32_bf16(
                            ah[i], bh[j], acc[i][j], 0, 0, 0);
                #pragma unroll
                for (int i = 0; i < 4; i++)
                    al[i] = *(const bf16x8*)&As_lo[(wm + i*16 + lm)*LDSROW + koff];
                #pragma unroll
                for (int i = 0; i < 4; i++)
                    #pragma unroll
                    for (int j = 0; j < 4; j++)
                        acc[i][j] = __builtin_amdgcn_mfma_f32_16x16x32_bf16(
                            al[i], bh[j], acc[i][j], 0, 0, 0);
                #pragma unroll
                for (int j = 0; j < 4; j++)
                    bl[j] = *(const bf16x8*)&Bs_lo[(wn + j*16 + lm)*LDSROW + koff];
                #pragma unroll
                for (int i = 0; i < 4; i++)
                    #pragma unroll
                    for (int j = 0; j < 4; j++)
                        acc[i][j] = __builtin_amdgcn_mfma_f32_16x16x32_bf16(
                            ah[i], bl[j], acc[i][j], 0, 0, 0);
            }
            __syncthreads();
        }
    }
    if (MODE == 1) {
        // shortcut: 1x1 conv over raw X (16 chunks, split in-kernel)
        for (int cc = 0; cc < 16; ++cc) {
            {
                const size_t tb = ((size_t)(cc*8 + bm) << 12) + tid*16;
                uint4 h0 = *(const uint4*)(Dh + tb);
                uint4 h1 = *(const uint4*)(Dh + tb + 8);
                uint4 l0 = *(const uint4*)(Dl + tb);
                uint4 l1 = *(const uint4*)(Dl + tb + 8);
                *(uint4*)&As_hi[aoff]     = h0;
                *(uint4*)&As_hi[aoff + 8] = h1;
                *(uint4*)&As_lo[aoff]     = l0;
                *(uint4*)&As_lo[aoff + 8] = l1;
            }
            {
                const float* src = Xf + ((size_t)bnimg*C_IN + cc*32 + half16)*SP + bp;
                unsigned v[16];
                #pragma unroll
                for (int e = 0; e < 16; ++e) v[e] = splitpack(src[e*SP]);
                unsigned hp[8], lp[8];
                #pragma unroll
                for (int j2 = 0; j2 < 8; ++j2) {
                    unsigned p0 = v[2*j2], p1 = v[2*j2+1];
                    hp[j2] = (p0 & 0xFFFFu) | (p1 << 16);
                    lp[j2] = (p0 >> 16) | (p1 & 0xFFFF0000u);
                }
                *(uint4*)&Bs_hi[bo]     = *(uint4*)&hp[0];
                *(uint4*)&Bs_hi[bo + 8] = *(uint4*)&hp[4];
                *(uint4*)&Bs_lo[bo]     = *(uint4*)&lp[0];
                *(uint4*)&Bs_lo[bo + 8] = *(uint4*)&lp[4];
            }
            __syncthreads();
            {
                bf16x8 ah[4], bh[4], al[4], bl[4];
                #pragma unroll
                for (int i = 0; i < 4; i++)
                    ah[i] = *(const bf16x8*)&As_hi[(wm + i*16 + lm)*LDSROW + koff];
                #pragma unroll
                for (int j = 0; j < 4; j++)
                    bh[j] = *(const bf16x8*)&Bs_hi[(wn + j*16 + lm)*LDSROW + koff];
                #pragma unroll
                for (int i = 0; i < 4; i++)
                    #pragma unroll
                    for (int j = 0; j < 4; j++)
                        acc[i][j] = __builtin_amdgcn_mfma_f32_16x16x32_bf16(
                            ah[i], bh[j], acc[i][j], 0, 0, 0);
                #pragma unroll
                for (int i = 0; i < 4; i++)
                    al[i] = *(const bf16x8*)&As_lo[(wm + i*16 + lm)*LDSROW + koff];
                #pragma unroll
                for (int i = 0; i < 4; i++)
                    #pragma unroll
                    for (int j = 0; j < 4; j++)
                        acc[i][j] = __builtin_amdgcn_mfma_f32_16x16x32_bf16(
                            al[i], bh[j], acc[i][j], 0, 0, 0);
                #pragma unroll
                for (int j = 0; j < 4; j++)
                    bl[j] = *(const bf16x8*)&Bs_lo[(wn + j*16 + lm)*LDSROW + koff];
                #pragma unroll
                for (int i = 0; i < 4; i++)
                    #pragma unroll
                    for (int j = 0; j < 4; j++)
                        acc[i][j] = __builtin_amdgcn_mfma_f32_16x16x32_bf16(
                            ah[i], bl[j], acc[i][j], 0, 0, 0);
            }
            __syncthreads();
        }
    }

    // ---- epilogue: relu; MODE0 packs h hi/lo uint, MODE1 stores fp32 ----
    // C/D layout (m89-verified): col = lane&15, row = (lane>>4)*4 + reg.
    #pragma unroll
    for (int j = 0; j < 4; j++) {
        const int gc = bn*128 + wn + j*16 + lm;
        const int n = gc / SP;
        const int p = gc - n*SP;
        #pragma unroll
        for (int i = 0; i < 4; i++) {
            #pragma unroll
            for (int r = 0; r < 4; r++) {
                const int m = bm*128 + wm + i*16 + lq*4 + r;
                float val = fmaxf(acc[i][j][r], 0.f);
                if (MODE == 0)
                    outU[((size_t)n*C_MID + m)*SP + p] = splitpack(val);
                else
                    outF[((size_t)n*C_MID + m)*SP + p] = val;
            }
        }
    }
}

// ---------------------------------------------------------------------------
__global__ __launch_bounds__(256)
void pool_kernel(const float* __restrict__ emb, float* __restrict__ flat)
{
    int n = blockIdx.x;
    for (int c = threadIdx.x; c < C_MID; c += 256) {
        const float* p = emb + ((size_t)n*C_MID + c)*SP;
        float s = 0.f;
        #pragma unroll
        for (int i = 0; i < SP; i++) s += p[i];
        flat[n*C_MID + c] = s / 49.0f;
    }
}

// ---------------------------------------------------------------------------
__global__ __launch_bounds__(64)
void head_kernel(const float* __restrict__ flat,
                 const float* __restrict__ cls_w, const float* __restrict__ cls_b,
                 const float* __restrict__ reg_w, const float* __restrict__ reg_b,
                 const float* __restrict__ props,
                 float* __restrict__ cls_out, float* __restrict__ reg_out,
                 float* __restrict__ pbox, float* __restrict__ pscore)
{
    int n = blockIdx.x;
    __shared__ float f[C_MID];
    __shared__ float logits[9];
    __shared__ float regs[36];
    for (int c = threadIdx.x; c < C_MID; c += 64) f[c] = flat[n*C_MID + c];
    __syncthreads();
    int o = threadIdx.x;
    if (o < 45) {
        const float* w = (o < 9) ? (cls_w + o*C_MID) : (reg_w + (o-9)*C_MID);
        float a = (o < 9) ? cls_b[o] : reg_b[o-9];
        for (int c = 0; c < C_MID; c++) a = fmaf(f[c], w[c], a);
        if (o < 9) { cls_out[n*9 + o] = a; logits[o] = a; }
        else       { reg_out[n*36 + (o-9)] = a; regs[o-9] = a; }
    }
    __syncthreads();
    if (o < 9) {
        float m = logits[0];
        for (int i = 1; i < 9; i++) m = fmaxf(m, logits[i]);
        float se = 0.f;
        for (int i = 0; i < 9; i++) se += expf(logits[i] - m);
        pscore[n*9 + o] = expf(logits[o] - m) / se;
        {
            #pragma clang fp contract(off)
            float x1 = props[n*4+0], y1 = props[n*4+1];
            float x2 = props[n*4+2], y2 = props[n*4+3];
            float pw = x2 - x1, ph = y2 - y1;
            float pcx = x1 + 0.5f*pw, pcy = y1 + 0.5f*ph;
            float dx = regs[o*4+0] / 10.0f;
            float dy = regs[o*4+1] / 10.0f;
            float dw = fminf(regs[o*4+2] / 5.0f, 4.135166556742356f);
            float dh = fminf(regs[o*4+3] / 5.0f, 4.135166556742356f);
            float ncx = dx*pw + pcx, ncy = dy*ph + pcy;
            float nw = expf(dw)*pw,  nh = expf(dh)*ph;
            float bx1 = ncx - 0.5f*nw, by1 = ncy - 0.5f*nh;
            float bx2 = ncx + 0.5f*nw, by2 = ncy + 0.5f*nh;
            bx1 = fminf(fmaxf(bx1, 0.f), 640.f);
            by1 = fminf(fmaxf(by1, 0.f), 384.f);
            bx2 = fminf(fmaxf(bx2, 0.f), 640.f);
            by2 = fminf(fmaxf(by2, 0.f), 384.f);
            float* dst = pbox + (n*9 + o)*4;
            dst[0] = bx1; dst[1] = by1; dst[2] = bx2; dst[3] = by2;
        }
    }
}

// ---------------------------------------------------------------------------
__global__ __launch_bounds__(1024)
void nms_kernel(const float* __restrict__ pbox, const float* __restrict__ pscore,
                float* __restrict__ dbox, float* __restrict__ dsc,
                float* __restrict__ dlab, float* __restrict__ dval)
{
    #pragma clang fp contract(off)
    const int b = blockIdx.x;
    const int tid = threadIdx.x;
    __shared__ unsigned long long mbuf[4096];
    __shared__ float s512[512];
    __shared__ int   id512[512];
    __shared__ float obx[512][4];
    __shared__ unsigned long long keepw[8];
    float* sc = (float*)mbuf;
    int*   si = (int*)(sc + 4096);
    const float NEG_INF = -__builtin_inff();

    for (int i = tid; i < 4096; i += 1024) {
        int p = i >> 3;
        int c = (i & 7) + 1;
        int n = b*512 + p;
        float s = pscore[n*9 + c];
        const float* bb = pbox + (n*9 + c)*4;
        float w = bb[2] - bb[0], h = bb[3] - bb[1];
        bool valid = (s > 0.05f) && (w >= 0.01f) && (h >= 0.01f);
        sc[i] = valid ? s : NEG_INF;
        si[i] = i;
    }
    __syncthreads();
    for (int k = 2; k <= 4096; k <<= 1) {
        for (int j = k >> 1; j > 0; j >>= 1) {
            for (int i = tid; i < 4096; i += 1024) {
                int ixj = i ^ j;
                if (ixj > i) {
                    float s1 = sc[i], s2 = sc[ixj];
                    int i1 = si[i], i2 = si[ixj];
                    bool before12 = (s1 > s2) || ((s1 == s2) && (i1 < i2));
                    bool up = ((i & k) == 0);
                    if (up ? !before12 : before12) {
                        sc[i] = s2; sc[ixj] = s1;
                        si[i] = i2; si[ixj] = i1;
                    }
                }
            }
            __syncthreads();
        }
    }
    if (tid < 512) {
        float s = sc[tid];
        int id = si[tid];
        s512[tid] = s;
        id512[tid] = id;
        int c = (id & 7) + 1;
        int n = b*512 + (id >> 3);
        float off = (float)c * 641.0f;
        const float* bb = pbox + (n*9 + c)*4;
        obx[tid][0] = bb[0] + off;
        obx[tid][1] = bb[1] + off;
        obx[tid][2] = bb[2] + off;
        obx[tid][3] = bb[3] + off;
    }
    __syncthreads();
    unsigned long long* mask = mbuf;
    for (int idx = tid; idx < 4096; idx += 1024) {
        int i = idx >> 3, w = idx & 7;
        float ax1 = obx[i][0], ay1 = obx[i][1], ax2 = obx[i][2], ay2 = obx[i][3];
        float aarea = (ax2 - ax1) * (ay2 - ay1);
        unsigned long long m = 0;
        int j0 = w << 6;
        for (int jj = 0; jj < 64; jj++) {
            int j = j0 + jj;
            if (j > i) {
                float bx1 = obx[j][0], by1 = obx[j][1];
                float bx2 = obx[j][2], by2 = obx[j][3];
                float barea = (bx2 - bx1) * (by2 - by1);
                float lx = fmaxf(ax1, bx1), ly = fmaxf(ay1, by1);
                float rx = fminf(ax2, bx2), ry = fminf(ay2, by2);
                float iw = fmaxf(rx - lx, 0.f), ih = fmaxf(ry - ly, 0.f);
                float inter = iw * ih;
                float iou = inter / fmaxf(aarea + barea - inter, 1e-8f);
                if (iou > 0.5f) m |= (1ull << jj);
            }
        }
        mask[(i << 3) + w] = m;
    }
    if (tid < 8) {
        unsigned long long kw = 0;
        for (int jj = 0; jj < 64; jj++)
            if (s512[(tid << 6) + jj] != NEG_INF) kw |= (1ull << jj);
        keepw[tid] = kw;
    }
    __syncthreads();
    if (tid == 0) {
        for (int i = 0; i < 512; i++) {
            if ((keepw[i >> 6] >> (i & 63)) & 1ull) {
                const unsigned long long* mi = mask + (i << 3);
                #pragma unroll
                for (int w = 0; w < 8; w++) keepw[w] &= ~mi[w];
            }
        }
        int cnt = 0;
        for (int i = 0; i < 512 && cnt < 100; i++) {
            if ((keepw[i >> 6] >> (i & 63)) & 1ull) {
                int id = id512[i];
                int c = (id & 7) + 1;
                int n = b*512 + (id >> 3);
                const float* bb = pbox + (n*9 + c)*4;
                float* db = dbox + (b*100 + cnt)*4;
                db[0] = bb[0]; db[1] = bb[1]; db[2] = bb[2]; db[3] = bb[3];
                dsc[b*100 + cnt] = s512[i];
                dlab[b*100 + cnt] = (float)c;
                dval[b*100 + cnt] = 1.0f;
                cnt++;
            }
        }
        for (; cnt < 100; cnt++) {
            float* db = dbox + (b*100 + cnt)*4;
            db[0] = 0.f; db[1] = 0.f; db[2] = 0.f; db[3] = 0.f;
            dsc[b*100 + cnt] = 0.f;
            dlab[b*100 + cnt] = 0.f;
            dval[b*100 + cnt] = 0.f;
        }
    }
}

// ---------------------------------------------------------------------------
extern "C" void kernel_launch(void* const* d_in, const int* in_sizes, int n_in,
                              void* d_out, int out_size, void* d_ws, size_t ws_size,
                              hipStream_t stream)
{
    const float* X      = (const float*)d_in[0];
    const float* props  = (const float*)d_in[1];
    const float* w1     = (const float*)d_in[2];
    const float* w2     = (const float*)d_in[3];
    const float* wd     = (const float*)d_in[4];
    const float* cls_w  = (const float*)d_in[5];
    const float* cls_b  = (const float*)d_in[6];
    const float* reg_w  = (const float*)d_in[7];
    const float* reg_b  = (const float*)d_in[8];

    float* out     = (float*)d_out;
    float* emb     = out;                        // 51380224 floats
    float* cls_out = out + 51380224;
    float* reg_out = cls_out + 9216;
    float* dbox    = reg_out + 36864;
    float* dsc     = dbox + 800;
    float* dlab    = dsc + 200;
    float* dval    = dlab + 200;

    // conv1-lifetime scratch inside the emb region (overwritten by conv2):
    unsigned* Xpk            = (unsigned*)out;             // 25,690,112 uints
    unsigned short* Wpk1h    = (unsigned short*)(out + 25690112); // 4,718,592 ush
    unsigned short* Wpk1l    = (unsigned short*)(out + 30408704); // 4,718,592 ush
    // (ends at float offset 35,127,296 < 51,380,224)

    char* wsb = (char*)d_ws;
    unsigned* h_u         = (unsigned*)(wsb);                       // 205,520,896 B
    unsigned short* Wpk2h = (unsigned short*)(wsb + 205520896);     // 18,874,368 B
    unsigned short* Wpk2l = (unsigned short*)(wsb + 224395264);     // 18,874,368 B
    unsigned short* Wpkdh = (unsigned short*)(wsb + 243269632);     //  1,048,576 B
    unsigned short* Wpkdl = (unsigned short*)(wsb + 244318208);     //  1,048,576 B
    float* flat           = (float*)(wsb + 245366784);              //  4,194,304 B
    float* pbox           = (float*)(wsb + 249561088);              //    147,456 B
    float* pscore         = (float*)(wsb + 249708544);              //     36,864 B

    pack_x <<<100352, 256, 0, stream>>>(X, Xpk);
    pack_w1<<<18432,  256, 0, stream>>>(w1, Wpk1h, Wpk1l);
    pack_w2<<<36864,  256, 0, stream>>>(w2, Wpk2h, Wpk2l);
    pack_wd<<<2048,   256, 0, stream>>>(wd, Wpkdh, Wpkdl);

    dim3 cgrid(NCOLS/128, C_MID/128);
    conv_mfma<0><<<cgrid, 256, 0, stream>>>(Xpk, X, Wpk1h, Wpk1l,
                                            nullptr, nullptr, nullptr, h_u);
    conv_mfma<1><<<cgrid, 256, 0, stream>>>(h_u, X, Wpk2h, Wpk2l,
                                            Wpkdh, Wpkdl, emb, nullptr);
    pool_kernel<<<N_IMG, 256, 0, stream>>>(emb, flat);
    head_kernel<<<N_IMG, 64, 0, stream>>>(flat, cls_w, cls_b, reg_w, reg_b, props,
                                          cls_out, reg_out, pbox, pscore);
    nms_kernel<<<2, 1024, 0, stream>>>(pbox, pscore, dbox, dsc, dlab, dval);
}